// Round 9
// baseline (557.493 us; speedup 1.0000x reference)
//
#include <hip/hip_runtime.h>
#include <hip/hip_cooperative_groups.h>

namespace cg = cooperative_groups;

#define NN 100000
#define NE 1600000
#define NPAD 100352        // rowptr allocation
#define NROWS 100096       // padded node rows (1564*64)
#define NBKT 391           // buckets of 256 nodes
#define SENT NBKT          // sentinel slot (never atomically touched)
#define EPB 4096           // edges per build block
#define MAXB 6144          // LDS edge capacity in fill (mean 4092, +32 sigma)

typedef __attribute__((ext_vector_type(8))) short short8;
typedef __attribute__((ext_vector_type(4))) float float4v;

__device__ inline unsigned short f2bf(float f)
{
    union { float f; unsigned u; } v; v.f = f;
    unsigned r = v.u + 0x7FFF + ((v.u >> 16) & 1);
    return (unsigned short)(r >> 16);
}
__device__ inline float bf2f(unsigned short h)
{
    union { unsigned u; float f; } v; v.u = ((unsigned)h) << 16; return v.f;
}

// ---------------------------------------------------------------------------
// Cooperative build: ONE dispatch does cast + Wcat + bucket hist ->
// grid.sync -> scan + reserve + scatter -> grid.sync -> per-bucket counting
// sort (rowptr + node-sorted colb). LDS hist/scan persist across syncs.
// Counters are poison-relative (sentinel slot never touched).
// ---------------------------------------------------------------------------
__global__ __launch_bounds__(512) void coop_build_kernel(
    const int* __restrict__ src, const int* __restrict__ dst,
    const float* __restrict__ x,
    const float* __restrict__ Ws1, const float* __restrict__ Wn1,
    const float* __restrict__ Ws2, const float* __restrict__ Wn2,
    unsigned short* __restrict__ XF,
    unsigned short* __restrict__ W1, unsigned short* __restrict__ W2,
    int* __restrict__ bdeg, int* __restrict__ bcur,
    int* __restrict__ colb, int* __restrict__ rowptr)
{
    cg::grid_group grid = cg::this_grid();
    __shared__ int lh[NBKT];
    __shared__ int sc[512];
    __shared__ int ex[512];
    __shared__ int eb[MAXB];
    __shared__ int cnt[256];
    __shared__ int bb2[2];

    const int tid = threadIdx.x;
    const int b = blockIdx.x;
    const int base = b * EPB;
    const int bend = min(base + EPB, NE);

    // ---- Stage 0: LDS hist (+ cast / wcat / zero-row overlap) ----
    for (int i = tid; i < NBKT; i += 512) lh[i] = 0;
    __syncthreads();
    for (int e = base + tid; e < bend; e += 512)
        atomicAdd(&lh[dst[e] >> 8], 1);

    // cast slice: strided over all 391*512 threads
    for (int t = b * 512 + tid; t < NN * 16; t += NBKT * 512) {
        int n = t >> 4;
        int k4 = (t & 15) * 4;
        float4 v = *(const float4*)(x + (size_t)n * 64 + k4);
        ushort4 o;
        o.x = f2bf(v.x); o.y = f2bf(v.y); o.z = f2bf(v.z); o.w = f2bf(v.w);
        *(ushort4*)(XF + (size_t)n * 64 + k4) = o;
    }
    if (b == 0) {
        for (int id = tid; id < 16384; id += 512) {
            int l = id >> 13;
            int r = id & 8191;
            int o = r >> 7, k = r & 127;
            const float* Ws = l ? Ws2 : Ws1;
            const float* Wn = l ? Wn2 : Wn1;
            float v = (k < 64) ? Ws[o * 64 + k] : Wn[o * 64 + (k - 64)];
            (l ? W2 : W1)[r] = f2bf(v);
        }
        if (tid < 16) {
            ushort4 z; z.x = 0; z.y = 0; z.z = 0; z.w = 0;
            *(ushort4*)(XF + (size_t)NN * 64 + tid * 4) = z;
        }
    }
    __syncthreads();
    for (int i = tid; i < NBKT; i += 512) {
        int c = lh[i];
        if (c) atomicAdd(&bdeg[i], c);          // on top of uniform poison
    }
    __threadfence();
    grid.sync();

    // ---- Stage 1: global bucket scan, reserve ranges, scatter ----
    int initd = bdeg[SENT];
    int v = (tid < NBKT) ? (int)((unsigned)bdeg[tid] - (unsigned)initd) : 0;
    sc[tid] = v;
    __syncthreads();
    #pragma unroll
    for (int off = 1; off < 512; off <<= 1) {
        int u = (tid >= off) ? sc[tid - off] : 0;
        __syncthreads();
        sc[tid] += u;
        __syncthreads();
    }
    ex[tid] = sc[tid] - v;
    __syncthreads();

    int initc = bcur[SENT];
    for (int i = tid; i < NBKT; i += 512) {
        int c = lh[i];
        if (c) {
            int old = atomicAdd(&bcur[i], c);
            lh[i] = ex[i] + (int)((unsigned)old - (unsigned)initc);
        }
    }
    __syncthreads();
    for (int e = base + tid; e < bend; e += 512) {
        int d = dst[e];
        int p = atomicAdd(&lh[d >> 8], 1);
        colb[p] = (src[e] << 8) | (d & 255);
    }
    __threadfence();
    grid.sync();

    // ---- Stage 2: per-bucket counting sort (block b = bucket b) ----
    if (tid == b) { bb2[0] = ex[tid]; bb2[1] = sc[tid] - ex[tid]; }
    __syncthreads();
    const int beg = bb2[0];
    const int m = min(bb2[1], MAXB);

    for (int r = tid; r < m; r += 512) eb[r] = colb[beg + r];
    if (tid < 256) cnt[tid] = 0;
    __syncthreads();
    for (int r = tid; r < m; r += 512)
        atomicAdd(&cnt[eb[r] & 255], 1);
    __syncthreads();

    int v2 = (tid < 256) ? cnt[tid] : 0;
    sc[tid] = (tid < 256) ? v2 : 0;
    __syncthreads();
    #pragma unroll
    for (int off = 1; off < 256; off <<= 1) {
        int u = (tid >= off && tid < 256) ? sc[tid - off] : 0;
        __syncthreads();
        if (tid < 256) sc[tid] += u;
        __syncthreads();
    }
    if (tid < 256) {
        int nodebase = beg + sc[tid] - v2;
        rowptr[b * 256 + tid] = nodebase;
        cnt[tid] = nodebase;
    }
    __syncthreads();
    for (int r = tid; r < m; r += 512) {
        int pk = eb[r];
        int pos = atomicAdd(&cnt[pk & 255], 1);
        colb[pos] = (pk >> 8) << 6;             // src*64, ready for aggregate
    }
}

// ---------------------------------------------------------------------------
// Fused aggregate + dense. Block = 64 nodes, 256 threads.
// Phase A: wave w aggregates nodes w*16..+15. Pipelined: rowptr hoisted via
//          one coalesced load + shfl; node i+1's edge-index vector prefetched
//          while node i accumulates (16 edges / 4 gathers in flight).
// Phase B: MFMA 16x64 per wave, A = [XIN | HN] rows, B = Wcat.
// ---------------------------------------------------------------------------
template <int LAYER1>
__global__ __launch_bounds__(256) void aggdense_kernel(
    const unsigned short* __restrict__ XIN,    // features, stride 64
    const int* __restrict__ rowptr,
    const int* __restrict__ colb,
    unsigned short* __restrict__ HN,           // hn scratch, stride 64
    const unsigned short* __restrict__ Wcat,
    const float* __restrict__ bias,
    unsigned short* __restrict__ xout,         // H1 (layer1)
    float* __restrict__ fout)                  // out (layer2)
{
    const int tid = threadIdx.x;
    const int wave = tid >> 6;
    const int lane = tid & 63;
    const int g = lane >> 4;
    const int q = lane & 15;
    const int ZOFF = NN * 64;
    const int nbase = blockIdx.x * 64 + wave * 16;

    // ---- Phase A ----
    int rp = 0;
    if (lane < 17) rp = rowptr[nbase + lane];  // tail entry may be junk; unused

    int beg = __shfl(rp, 0, 64);
    int end = __shfl(rp, 1, 64);
    if (nbase >= NN) { beg = 0; end = 0; }
    int cnt0 = min(end - beg, 64);
    int ci = (lane < cnt0) ? colb[beg + lane] : ZOFF;

    for (int i = 0; i < 16; ++i) {
        const int n = nbase + i;
        const int begC = beg, endC = end, cntC = cnt0;
        const int ciC = ci;
        if (i < 15) {                          // prefetch next node's indices
            int b1 = __shfl(rp, i + 1, 64);
            int e1 = __shfl(rp, i + 2, 64);
            if (n + 1 >= NN) { b1 = 0; e1 = 0; }
            beg = b1; end = e1;
            cnt0 = min(e1 - b1, 64);
            ci = (lane < cnt0) ? colb[b1 + lane] : ZOFF;
        }
        if (n < NN) {
            float a0 = 0.f, a1 = 0.f, a2 = 0.f, a3 = 0.f;
            for (int t = 0; t < cntC; t += 16) {
                int i0 = __shfl(ciC, t + g, 64);
                int i1 = __shfl(ciC, t + 4 + g, 64);
                int i2 = __shfl(ciC, t + 8 + g, 64);
                int i3 = __shfl(ciC, t + 12 + g, 64);
                ushort4 v0 = *(const ushort4*)(XIN + i0 + q * 4);
                ushort4 v1 = *(const ushort4*)(XIN + i1 + q * 4);
                ushort4 v2 = *(const ushort4*)(XIN + i2 + q * 4);
                ushort4 v3 = *(const ushort4*)(XIN + i3 + q * 4);
                a0 += bf2f(v0.x) + bf2f(v1.x) + bf2f(v2.x) + bf2f(v3.x);
                a1 += bf2f(v0.y) + bf2f(v1.y) + bf2f(v2.y) + bf2f(v3.y);
                a2 += bf2f(v0.z) + bf2f(v1.z) + bf2f(v2.z) + bf2f(v3.z);
                a3 += bf2f(v0.w) + bf2f(v1.w) + bf2f(v2.w) + bf2f(v3.w);
            }
            for (int j = begC + 64; j < endC; j += 64) {   // rare deg>64 tail
                int cc = min(endC - j, 64);
                int ci2 = (lane < cc) ? colb[j + lane] : ZOFF;
                for (int t = 0; t < cc; t += 16) {
                    int i0 = __shfl(ci2, t + g, 64);
                    int i1 = __shfl(ci2, t + 4 + g, 64);
                    int i2 = __shfl(ci2, t + 8 + g, 64);
                    int i3 = __shfl(ci2, t + 12 + g, 64);
                    ushort4 v0 = *(const ushort4*)(XIN + i0 + q * 4);
                    ushort4 v1 = *(const ushort4*)(XIN + i1 + q * 4);
                    ushort4 v2 = *(const ushort4*)(XIN + i2 + q * 4);
                    ushort4 v3 = *(const ushort4*)(XIN + i3 + q * 4);
                    a0 += bf2f(v0.x) + bf2f(v1.x) + bf2f(v2.x) + bf2f(v3.x);
                    a1 += bf2f(v0.y) + bf2f(v1.y) + bf2f(v2.y) + bf2f(v3.y);
                    a2 += bf2f(v0.z) + bf2f(v1.z) + bf2f(v2.z) + bf2f(v3.z);
                    a3 += bf2f(v0.w) + bf2f(v1.w) + bf2f(v2.w) + bf2f(v3.w);
                }
            }
            a0 += __shfl_xor(a0, 16, 64); a0 += __shfl_xor(a0, 32, 64);
            a1 += __shfl_xor(a1, 16, 64); a1 += __shfl_xor(a1, 32, 64);
            a2 += __shfl_xor(a2, 16, 64); a2 += __shfl_xor(a2, 32, 64);
            a3 += __shfl_xor(a3, 16, 64); a3 += __shfl_xor(a3, 32, 64);
            float rdeg = 1.0f / fmaxf((float)(endC - begC), 1.0f);
            if (g == 0) {
                ushort4 o;
                o.x = f2bf(a0 * rdeg); o.y = f2bf(a1 * rdeg);
                o.z = f2bf(a2 * rdeg); o.w = f2bf(a3 * rdeg);
                *(ushort4*)(HN + (size_t)n * 64 + q * 4) = o;
            }
        }
    }
    __syncthreads();

    // ---- Phase B: dense MFMA ----
    const int mrow = lane & 15;
    const int kb = lane >> 4;
    const int row0 = nbase;

    short8 a[4];
    {
        const short* ax = (const short*)XIN + (size_t)(row0 + mrow) * 64 + kb * 8;
        const short* ah = (const short*)HN + (size_t)(row0 + mrow) * 64 + kb * 8;
        a[0] = *(const short8*)(ax);
        a[1] = *(const short8*)(ax + 32);
        a[2] = *(const short8*)(ah);
        a[3] = *(const short8*)(ah + 32);
    }

    float4v acc[4];
    #pragma unroll
    for (int c = 0; c < 4; ++c) acc[c] = (float4v){0.f, 0.f, 0.f, 0.f};

    #pragma unroll
    for (int c = 0; c < 4; ++c) {
        const short* brow = (const short*)Wcat + (c * 16 + mrow) * 128 + kb * 8;
        #pragma unroll
        for (int i = 0; i < 4; ++i) {
            short8 bfr = *(const short8*)(brow + i * 32);
            acc[c] = __builtin_amdgcn_mfma_f32_16x16x32_bf16(a[i], bfr, acc[c], 0, 0, 0);
        }
    }

    const int rbase = row0 + (lane >> 4) * 4;
    #pragma unroll
    for (int c = 0; c < 4; ++c) {
        int o = c * 16 + mrow;
        float bv = bias[o];
        #pragma unroll
        for (int r = 0; r < 4; ++r) {
            int node = rbase + r;
            float val = acc[c][r] + bv;
            if (LAYER1) {
                float h = (node < NN) ? fmaxf(val, 0.f) : 0.f;
                xout[(size_t)node * 64 + o] = f2bf(h);
            } else {
                if (node < NN) fout[(size_t)node * 64 + o] = val;
            }
        }
    }
}

extern "C" void kernel_launch(void* const* d_in, const int* in_sizes, int n_in,
                              void* d_out, int out_size, void* d_ws, size_t ws_size,
                              hipStream_t stream)
{
    const float* in_feat = (const float*)d_in[0];
    const int*   src     = (const int*)d_in[1];
    const int*   dst     = (const int*)d_in[2];
    const float* Ws1     = (const float*)d_in[3];
    const float* Wn1     = (const float*)d_in[4];
    const float* b1      = (const float*)d_in[5];
    const float* Ws2     = (const float*)d_in[6];
    const float* Wn2     = (const float*)d_in[7];
    const float* b2      = (const float*)d_in[8];
    float* out = (float*)d_out;

    int* bdeg   = (int*)d_ws;                         // 512 (sentinel at 391)
    int* bcur   = bdeg + 512;                         // 512 (sentinel at 391)
    int* rowptr = bcur + 512;                         // NPAD
    int* colb   = rowptr + NPAD;                      // NE
    unsigned short* XF = (unsigned short*)(colb + NE);        // NROWS*64
    unsigned short* HN = XF + (size_t)NROWS * 64;             // NROWS*64
    unsigned short* H1 = HN + (size_t)NROWS * 64;             // NROWS*64
    unsigned short* W1 = H1 + (size_t)NROWS * 64;             // 8192
    unsigned short* W2 = W1 + 8192;                           // 8192

    // 1. cooperative build: cast + Wcat + hist -> scatter -> sort (1 dispatch)
    void* args[] = {
        (void*)&src, (void*)&dst, (void*)&in_feat,
        (void*)&Ws1, (void*)&Wn1, (void*)&Ws2, (void*)&Wn2,
        (void*)&XF, (void*)&W1, (void*)&W2,
        (void*)&bdeg, (void*)&bcur, (void*)&colb, (void*)&rowptr
    };
    hipLaunchCooperativeKernel((void*)coop_build_kernel,
                               dim3(NBKT), dim3(512), args, 0, stream);

    const int blocks = NROWS / 64;   // 1564

    // 2. layer 1: aggregate+dense fused
    aggdense_kernel<1><<<blocks, 256, 0, stream>>>(
        XF, rowptr, colb, HN, W1, b1, H1, nullptr);

    // 3. layer 2: aggregate+dense fused
    aggdense_kernel<0><<<blocks, 256, 0, stream>>>(
        H1, rowptr, colb, HN, W2, b2, nullptr, out);
}